// Round 5
// baseline (995.475 us; speedup 1.0000x reference)
//
#include <hip/hip_runtime.h>
#include <hip/hip_fp16.h>

typedef _Float16 half8 __attribute__((ext_vector_type(8)));
typedef float floatx4 __attribute__((ext_vector_type(4)));
typedef int intx4 __attribute__((ext_vector_type(4)));

#define NB 256   // batch
#define ND 256   // D
#define NL 256   // L (time)
#define NH 512   // H

// ---------------- Kernel 1: x_proj[b,d] = sum_l x[b,d,l] * Wx[l] ----------------
__global__ void k_xproj(const float* __restrict__ x, const float* __restrict__ Wattn,
                        float* __restrict__ xproj) {
    __shared__ float wx[NL];
    const int tid = threadIdx.x;
    wx[tid] = Wattn[2 * NH + tid];   // blockDim = 256 == NL
    __syncthreads();
    const int wid = tid >> 6, lane = tid & 63;
    const int row = blockIdx.x * 4 + wid;          // row = b*ND + d, 65536 rows
    const float4 v = ((const float4*)(x + (size_t)row * NL))[lane];
    float s = v.x * wx[lane * 4] + v.y * wx[lane * 4 + 1] +
              v.z * wx[lane * 4 + 2] + v.w * wx[lane * 4 + 3];
    #pragma unroll
    for (int off = 32; off; off >>= 1) s += __shfl_down(s, off);
    if (lane == 0) xproj[row] = s;
}

// ---------------- Kernel 2: attn[b,:] = softmax(x_proj[b,:]) ----------------
__global__ void k_softmax(const float* __restrict__ xproj, float* __restrict__ attn) {
    const int b = blockIdx.x, tid = threadIdx.x;
    __shared__ float red[8];
    float v = xproj[b * ND + tid];
    float m = v;
    #pragma unroll
    for (int off = 32; off; off >>= 1) m = fmaxf(m, __shfl_down(m, off));
    const int wid = tid >> 6, lane = tid & 63;
    if (lane == 0) red[wid] = m;
    __syncthreads();
    if (tid == 0) {
        float mm = fmaxf(fmaxf(red[0], red[1]), fmaxf(red[2], red[3]));
        red[4] = mm;
    }
    __syncthreads();
    const float e = expf(v - red[4]);
    float s = e;
    #pragma unroll
    for (int off = 32; off; off >>= 1) s += __shfl_down(s, off);
    if (lane == 0) red[wid] = s;
    __syncthreads();
    if (tid == 0) red[5] = red[0] + red[1] + red[2] + red[3];
    __syncthreads();
    attn[b * ND + tid] = e / red[5];
}

// ---- Kernel 3: ws[b,t,d] = attn[b,d]*x[b,d,t] (fp32 out) ; w16[t,b,d] = fp16(same) ----
__global__ void k_trans(const float* __restrict__ x, const float* __restrict__ attn,
                        float* __restrict__ ws_out, _Float16* __restrict__ w16) {
    __shared__ float tile[64][65];
    const int bid = blockIdx.x;
    const int b = bid >> 4, ti = (bid >> 2) & 3, tj = bid & 3;
    const int tx = threadIdx.x & 63, ty = threadIdx.x >> 6;
    const int d0 = ti * 64, l0 = tj * 64;
    const float* xb = x + ((size_t)b * ND + d0) * NL + l0;
    #pragma unroll
    for (int r = ty; r < 64; r += 4) tile[r][tx] = xb[(size_t)r * NL + tx];
    __syncthreads();
    const float af = attn[b * ND + d0 + tx];
    #pragma unroll
    for (int r = ty; r < 64; r += 4) {
        const int tt = l0 + r;
        const float val = af * tile[tx][r];
        ws_out[((size_t)b * NL + tt) * ND + d0 + tx] = val;
        w16[((size_t)tt * NB + b) * ND + d0 + tx] = (_Float16)val;
    }
}

// ---------------- Kernel 4: weight conversion (hi/lo split for W_hh) ----------------
__global__ void k_wsplit(const float* __restrict__ Whh, const float* __restrict__ Wih,
                         _Float16* __restrict__ hi, _Float16* __restrict__ lo,
                         _Float16* __restrict__ wih16) {
    const int idx = blockIdx.x * 256 + threadIdx.x;   // 4096*256 = 1048576 = 4H*H
    const float w = Whh[idx];
    const _Float16 h = (_Float16)w;
    hi[idx] = h;
    lo[idx] = (_Float16)(w - (float)h);
    if (idx < 4 * NH * ND) wih16[idx] = (_Float16)Wih[idx];
}

// ---------------- Kernel 5: persistent LSTM recurrence ----------------
// grid = 256 wgs x 512 thr. wg (m = bid&15, hb = bid>>4):
//   rows b in [16m, 16m+16), gate cols j = g*512 + hb*32 + [0,32) for g=0..3
// group = 16 wgs sharing m. Epoch-tagged h exchange (see R4 notes).
// R5 changes: (a) B-fragments pinned resident via inline-asm loads (no L2
// reload per step); (b) conflict-free lane-linear LDS staging; (c) stride-17
// acc exchange; (d) poll issued before accC, waited after; (e) w-prefetch
// pipelined one full iteration ahead.
__launch_bounds__(512, 2)
__global__ void k_recur(const _Float16* __restrict__ whhHi, const _Float16* __restrict__ whhLo,
                        const _Float16* __restrict__ wih16, const _Float16* __restrict__ w16,
                        const float* __restrict__ b_ih, const float* __restrict__ b_hh,
                        unsigned int* __restrict__ h32,   // [2][NB][NH] epoch-tagged
                        float* __restrict__ out_hs)       // [NB][NL][NH]
{
    __shared__ char smem[41472];
    // [0,16384)      : hLDS  [16 rows][1024B] fp16, XOR-swizzled (row&7)<<4
    // [16384,32768)  : wLDS  2 x [16 rows][512B] fp16, same swizzle
    // [32768,41472)  : accL  float[8][16][17]
    const int tid = threadIdx.x;
    const int wid = tid >> 6, lane = tid & 63;
    const int bid = blockIdx.x;
    const int m = bid & 15, hb = bid >> 4;
    const int b0 = m * 16;
    const int gate = wid >> 1, half = wid & 1;
    const int jb = gate * 512 + hb * 32 + half * 16;

    // --- persistent B fragments: inline-asm loads -> cannot be rematerialized ---
    half8 bhhH[16], bhhL[16], bihF[8];
    {
        const int bcol = jb + (lane & 15);
        const int krow = (lane >> 4) * 8;
        const _Float16* ph = whhHi + (size_t)bcol * NH + krow;
        const _Float16* pl = whhLo + (size_t)bcol * NH + krow;
        const _Float16* pw = wih16 + (size_t)bcol * ND + krow;
        #pragma unroll
        for (int kk = 0; kk < 16; ++kk) {
            asm volatile("global_load_dwordx4 %0, %1, off"
                         : "=v"(bhhH[kk]) : "v"(ph + kk * 32));
            asm volatile("global_load_dwordx4 %0, %1, off"
                         : "=v"(bhhL[kk]) : "v"(pl + kk * 32));
        }
        #pragma unroll
        for (int kk = 0; kk < 8; ++kk)
            asm volatile("global_load_dwordx4 %0, %1, off"
                         : "=v"(bihF[kk]) : "v"(pw + kk * 32));
        asm volatile("s_waitcnt vmcnt(0)" ::: "memory");
        __builtin_amdgcn_sched_barrier(0);
    }

    // --- cell-phase thread mapping: one (b, h_idx) per thread ---
    const int bl = tid >> 5, hl = tid & 31;
    float bias_[4];
    #pragma unroll
    for (int g = 0; g < 4; ++g) {
        const int j = g * 512 + hb * 32 + hl;
        bias_[g] = b_ih[j] + b_hh[j];
    }
    float c = 0.f;
    float* hsOut = out_hs + (size_t)(b0 + bl) * NL * NH + hb * 32 + hl;
    unsigned int* hWr = h32 + (size_t)(b0 + bl) * NH + hb * 32 + hl;  // + buf*NB*NH

    // A-frag read geometry
    const int arow = lane & 15;
    const int aq = (lane >> 4) * 16;     // byte offset of 16B chunk within 64B k-block
    const int aswz = (arow & 7) << 4;

    // poll/stage geometry: thread -> rows r1 = tid>>6 and r1+8, 16B payload each
    const int r1 = tid >> 6;                       // 0..7
    const int tagoff = (tid & 63) * 8;             // u32 index within row (8 u32 = 16B payload)
    const int hdst = (tid * 16) ^ (r1 << 4);       // conflict-free lane-linear + swizzle
    const int wrow = tid >> 5;                     // 0..15
    const int wdst = (tid * 16) ^ ((wrow & 7) << 4);

    // ---- prologue: stage w16[t=0] into wLDS[0]; prefetch w16[t=1] ----
    {
        const _Float16* wsrc = w16 + (size_t)(b0 + wrow) * ND + (tid & 31) * 8;
        *(intx4*)(smem + 16384 + wdst) = *(const intx4*)wsrc;
    }
    intx4 wpref;
    {
        const _Float16* wsrc = w16 + ((size_t)1 * NB + b0 + wrow) * ND + (tid & 31) * 8;
        asm volatile("global_load_dwordx4 %0, %1, off" : "=v"(wpref) : "v"(wsrc));
    }
    __syncthreads();

    #pragma unroll 1
    for (int t = 0; t < NL; ++t) {
        const int cur = t & 1, nxt = (t + 1) & 1;

        // ---- (1) issue poll loads for h_t (no wait yet) ----
        intx4 q0, q1, q2, q3;
        const unsigned int* p1 =
            h32 + (size_t)cur * NB * NH + (size_t)(b0 + r1) * NH + tagoff;
        const unsigned int* p2 = p1 + (size_t)8 * NH;
        if (t > 0) {
            asm volatile(
                "global_load_dwordx4 %0, %4, off sc0 sc1\n\t"
                "global_load_dwordx4 %1, %4, off offset:16 sc0 sc1\n\t"
                "global_load_dwordx4 %2, %5, off sc0 sc1\n\t"
                "global_load_dwordx4 %3, %5, off offset:16 sc0 sc1"
                : "=v"(q0), "=v"(q1), "=v"(q2), "=v"(q3)
                : "v"(p1), "v"(p2) : "memory");
        }

        // ---- (2) accC = w @ W_ih^T from wLDS[cur] (independent of h_t) ----
        floatx4 accC = {0.f, 0.f, 0.f, 0.f};
        #pragma unroll
        for (int kk = 0; kk < 8; ++kk) {
            const int waddr = 16384 + 8192 * cur + (((arow << 9) + (kk << 6) + aq) ^ aswz);
            const half8 a = *(const half8*)(smem + waddr);
            accC = __builtin_amdgcn_mfma_f32_16x16x32_f16(a, bihF[kk], accC, 0, 0, 0);
        }

        // ---- (3) wait + tag-check + (re-poll if stale) + stage to LDS ----
        if (t > 0) {
            asm volatile("s_waitcnt vmcnt(0)" ::: "memory");
            __builtin_amdgcn_sched_barrier(0);
            const unsigned int et = (unsigned int)t;
            bool ok = true;
            #pragma unroll
            for (int i = 0; i < 4; ++i) {
                ok &= (((unsigned int)q0[i]) >> 16) == et;
                ok &= (((unsigned int)q1[i]) >> 16) == et;
                ok &= (((unsigned int)q2[i]) >> 16) == et;
                ok &= (((unsigned int)q3[i]) >> 16) == et;
            }
            while (!ok) {
                asm volatile(
                    "global_load_dwordx4 %0, %4, off sc0 sc1\n\t"
                    "global_load_dwordx4 %1, %4, off offset:16 sc0 sc1\n\t"
                    "global_load_dwordx4 %2, %5, off sc0 sc1\n\t"
                    "global_load_dwordx4 %3, %5, off offset:16 sc0 sc1\n\t"
                    "s_waitcnt vmcnt(0)"
                    : "=v"(q0), "=v"(q1), "=v"(q2), "=v"(q3)
                    : "v"(p1), "v"(p2) : "memory");
                ok = true;
                #pragma unroll
                for (int i = 0; i < 4; ++i) {
                    ok &= (((unsigned int)q0[i]) >> 16) == et;
                    ok &= (((unsigned int)q1[i]) >> 16) == et;
                    ok &= (((unsigned int)q2[i]) >> 16) == et;
                    ok &= (((unsigned int)q3[i]) >> 16) == et;
                }
            }
            intx4 d0, d1;
            d0[0] = (q0[0] & 0xffff) | (q0[1] << 16);
            d0[1] = (q0[2] & 0xffff) | (q0[3] << 16);
            d0[2] = (q1[0] & 0xffff) | (q1[1] << 16);
            d0[3] = (q1[2] & 0xffff) | (q1[3] << 16);
            d1[0] = (q2[0] & 0xffff) | (q2[1] << 16);
            d1[1] = (q2[2] & 0xffff) | (q2[3] << 16);
            d1[2] = (q3[0] & 0xffff) | (q3[1] << 16);
            d1[3] = (q3[2] & 0xffff) | (q3[3] << 16);
            *(intx4*)(smem + hdst) = d0;
            *(intx4*)(smem + 8192 + hdst) = d1;
        } else {
            const intx4 z = {0, 0, 0, 0};
            *(intx4*)(smem + hdst) = z;
            *(intx4*)(smem + 8192 + hdst) = z;
        }
        // stage w prefetch (loaded last iteration; landed under the poll wait)
        *(intx4*)(smem + 16384 + 8192 * nxt + wdst) = wpref;
        // issue next w prefetch (w16[t+2]); lands during GEMM+cell
        {
            const int tp = (t + 2 < NL) ? t + 2 : NL - 1;
            const _Float16* wsrc =
                w16 + ((size_t)tp * NB + b0 + wrow) * ND + (tid & 31) * 8;
            asm volatile("global_load_dwordx4 %0, %1, off" : "=v"(wpref) : "v"(wsrc));
        }
        __syncthreads();

        // ---- (4) h GEMM: K=512 with hi/lo split weights ----
        floatx4 accA = {0.f, 0.f, 0.f, 0.f};
        floatx4 accB = {0.f, 0.f, 0.f, 0.f};
        #pragma unroll
        for (int kk = 0; kk < 16; ++kk) {
            const int aaddr = ((arow << 10) + (kk << 6) + aq) ^ aswz;
            const half8 a = *(const half8*)(smem + aaddr);
            accA = __builtin_amdgcn_mfma_f32_16x16x32_f16(a, bhhH[kk], accA, 0, 0, 0);
            accB = __builtin_amdgcn_mfma_f32_16x16x32_f16(a, bhhL[kk], accB, 0, 0, 0);
        }
        const floatx4 f = (accA + accB) + accC;

        // ---- (5) exchange acc tiles through LDS (stride 17: conflict-free) ----
        {
            float* accL = (float*)(smem + 32768);
            const int colw = lane & 15, rowq = (lane >> 4) * 4;
            #pragma unroll
            for (int r = 0; r < 4; ++r)
                accL[wid * 272 + (rowq + r) * 17 + colw] = f[r];
        }
        __syncthreads();

        // ---- (6) LSTM cell (one (b, h_idx) per thread; c in register) ----
        float h2;
        {
            const float* accL = (const float*)(smem + 32768);
            const int hq = hl >> 4, cidx = hl & 15;
            const int off = bl * 17 + cidx;
            const float pi = accL[(0 + hq) * 272 + off] + bias_[0];
            const float pf = accL[(2 + hq) * 272 + off] + bias_[1];
            const float pg = accL[(4 + hq) * 272 + off] + bias_[2];
            const float po = accL[(6 + hq) * 272 + off] + bias_[3];
            const float si = 1.f / (1.f + __expf(-pi));
            const float sf = 1.f / (1.f + __expf(-pf));
            const float so = 1.f / (1.f + __expf(-po));
            float e2 = __expf(-2.f * fabsf(pg));
            float tg = (1.f - e2) / (1.f + e2);
            tg = (pg < 0.f) ? -tg : tg;
            c = sf * c + si * tg;
            float e2c = __expf(-2.f * fabsf(c));
            float tc = (1.f - e2c) / (1.f + e2c);
            tc = (c < 0.f) ? -tc : tc;
            h2 = so * tc;
            // epoch-tagged h store (fire-and-forget, device-visible)
            const _Float16 hh = (_Float16)h2;
            const unsigned int hv =
                ((unsigned int)(t + 1) << 16) |
                (unsigned int)__builtin_bit_cast(unsigned short, hh);
            const void* hp = hWr + (size_t)nxt * NB * NH;
            asm volatile("global_store_dword %0, %1, off sc0 sc1"
                         :: "v"(hp), "v"(hv) : "memory");
        }
        hsOut[(size_t)t * NH] = h2;   // fire-and-forget HBM store
    }
}

extern "C" void kernel_launch(void* const* d_in, const int* in_sizes, int n_in,
                              void* d_out, int out_size, void* d_ws, size_t ws_size,
                              hipStream_t stream) {
    const float* x     = (const float*)d_in[0];
    const float* Wattn = (const float*)d_in[1];
    // d_in[2] = b_attn : provably unused (softmax shift invariance)
    const float* Wih   = (const float*)d_in[3];
    const float* Whh   = (const float*)d_in[4];
    const float* bih   = (const float*)d_in[5];
    const float* bhh   = (const float*)d_in[6];

    float* ws_out = (float*)d_out;                                 // [B][L][D]
    float* hs_out = ws_out + (size_t)NB * NL * ND;                 // [B][L][H]

    char* ws = (char*)d_ws;
    float*    attn  = (float*)(ws + 4096);                         // 256 KB
    float*    xproj = (float*)(ws + 4096 + 262144);                // 256 KB
    unsigned int* h32 = (unsigned int*)(ws + 1048576);             // 2 x 512 KB tagged
    _Float16* whhHi = (_Float16*)(ws + 2097152);                   // 2 MB
    _Float16* whhLo = (_Float16*)(ws + 2097152 + 2097152);         // 2 MB
    _Float16* wih16 = (_Float16*)(ws + 6291456);                   // 1 MB
    _Float16* w16   = (_Float16*)(ws + 8388608);                   // 33.5 MB

    // Clear epoch tags: prevents stale tag-255 collision across timed replays.
    hipMemsetAsync(h32, 0, (size_t)2 * NB * NH * 4, stream);

    k_xproj  <<<16384, 256, 0, stream>>>(x, Wattn, xproj);
    k_softmax<<<256,   256, 0, stream>>>(xproj, attn);
    k_trans  <<<4096,  256, 0, stream>>>(x, attn, ws_out, w16);
    k_wsplit <<<4096,  256, 0, stream>>>(Whh, Wih, whhHi, whhLo, wih16);
    k_recur  <<<256,   512, 0, stream>>>(whhHi, whhLo, wih16, w16, bih, bhh,
                                         h32, hs_out);
}

// Round 6
// 995.086 us; speedup vs baseline: 1.0004x; 1.0004x over previous
//
#include <hip/hip_runtime.h>
#include <hip/hip_fp16.h>

typedef _Float16 half8 __attribute__((ext_vector_type(8)));
typedef float floatx4 __attribute__((ext_vector_type(4)));
typedef int intx4 __attribute__((ext_vector_type(4)));

#define NB 256   // batch
#define ND 256   // D
#define NL 256   // L (time)
#define NH 512   // H

// ---------------- Kernel 1: x_proj[b,d] = sum_l x[b,d,l] * Wx[l] ----------------
__global__ void k_xproj(const float* __restrict__ x, const float* __restrict__ Wattn,
                        float* __restrict__ xproj) {
    __shared__ float wx[NL];
    const int tid = threadIdx.x;
    wx[tid] = Wattn[2 * NH + tid];   // blockDim = 256 == NL
    __syncthreads();
    const int wid = tid >> 6, lane = tid & 63;
    const int row = blockIdx.x * 4 + wid;          // row = b*ND + d, 65536 rows
    const float4 v = ((const float4*)(x + (size_t)row * NL))[lane];
    float s = v.x * wx[lane * 4] + v.y * wx[lane * 4 + 1] +
              v.z * wx[lane * 4 + 2] + v.w * wx[lane * 4 + 3];
    #pragma unroll
    for (int off = 32; off; off >>= 1) s += __shfl_down(s, off);
    if (lane == 0) xproj[row] = s;
}

// ---------------- Kernel 2: attn[b,:] = softmax(x_proj[b,:]) ----------------
__global__ void k_softmax(const float* __restrict__ xproj, float* __restrict__ attn) {
    const int b = blockIdx.x, tid = threadIdx.x;
    __shared__ float red[8];
    float v = xproj[b * ND + tid];
    float m = v;
    #pragma unroll
    for (int off = 32; off; off >>= 1) m = fmaxf(m, __shfl_down(m, off));
    const int wid = tid >> 6, lane = tid & 63;
    if (lane == 0) red[wid] = m;
    __syncthreads();
    if (tid == 0) {
        float mm = fmaxf(fmaxf(red[0], red[1]), fmaxf(red[2], red[3]));
        red[4] = mm;
    }
    __syncthreads();
    const float e = expf(v - red[4]);
    float s = e;
    #pragma unroll
    for (int off = 32; off; off >>= 1) s += __shfl_down(s, off);
    if (lane == 0) red[wid] = s;
    __syncthreads();
    if (tid == 0) red[5] = red[0] + red[1] + red[2] + red[3];
    __syncthreads();
    attn[b * ND + tid] = e / red[5];
}

// ---- Kernel 3: ws[b,t,d] = attn[b,d]*x[b,d,t] (fp32 out) ; w16[t,b,d] = fp16(same) ----
__global__ void k_trans(const float* __restrict__ x, const float* __restrict__ attn,
                        float* __restrict__ ws_out, _Float16* __restrict__ w16) {
    __shared__ float tile[64][65];
    const int bid = blockIdx.x;
    const int b = bid >> 4, ti = (bid >> 2) & 3, tj = bid & 3;
    const int tx = threadIdx.x & 63, ty = threadIdx.x >> 6;
    const int d0 = ti * 64, l0 = tj * 64;
    const float* xb = x + ((size_t)b * ND + d0) * NL + l0;
    #pragma unroll
    for (int r = ty; r < 64; r += 4) tile[r][tx] = xb[(size_t)r * NL + tx];
    __syncthreads();
    const float af = attn[b * ND + d0 + tx];
    #pragma unroll
    for (int r = ty; r < 64; r += 4) {
        const int tt = l0 + r;
        const float val = af * tile[tx][r];
        ws_out[((size_t)b * NL + tt) * ND + d0 + tx] = val;
        w16[((size_t)tt * NB + b) * ND + d0 + tx] = (_Float16)val;
    }
}

// ---------------- Kernel 4: weight conversion (hi/lo split for W_hh) ----------------
__global__ void k_wsplit(const float* __restrict__ Whh, const float* __restrict__ Wih,
                         _Float16* __restrict__ hi, _Float16* __restrict__ lo,
                         _Float16* __restrict__ wih16) {
    const int idx = blockIdx.x * 256 + threadIdx.x;   // 4096*256 = 1048576 = 4H*H
    const float w = Whh[idx];
    const _Float16 h = (_Float16)w;
    hi[idx] = h;
    lo[idx] = (_Float16)(w - (float)h);
    if (idx < 4 * NH * ND) wih16[idx] = (_Float16)Wih[idx];
}

// ---------------- Kernel 5: persistent LSTM recurrence ----------------
// grid = 256 wgs x 512 thr. wg (m = bid&15, hb = bid>>4):
//   rows b in [16m, 16m+16), gate cols j = g*512 + hb*32 + [0,32) for g=0..3
// group = 16 wgs sharing m. Epoch-tagged h exchange (see R4 notes).
// R6 change: __launch_bounds__(512) (NOT (512,2)) -> 256-VGPR cap, so the
// 40 B-fragments (160 VGPRs) stay genuinely resident. Grid is 1 wg/CU, so
// the old 2-blocks/CU promise bought nothing but a 128-VGPR cap, which
// forced per-step L2 refetch (R2/R4, ~2.4us/step) or scratch spill (R5).
__launch_bounds__(512)
__global__ void k_recur(const _Float16* __restrict__ whhHi, const _Float16* __restrict__ whhLo,
                        const _Float16* __restrict__ wih16, const _Float16* __restrict__ w16,
                        const float* __restrict__ b_ih, const float* __restrict__ b_hh,
                        unsigned int* __restrict__ h32,   // [2][NB][NH] epoch-tagged
                        float* __restrict__ out_hs)       // [NB][NL][NH]
{
    __shared__ char smem[41472];
    // [0,16384)      : hLDS  [16 rows][1024B] fp16, XOR-swizzled (row&7)<<4
    // [16384,32768)  : wLDS  2 x [16 rows][512B] fp16, same swizzle
    // [32768,41472)  : accL  float[8][16][17]
    const int tid = threadIdx.x;
    const int wid = tid >> 6, lane = tid & 63;
    const int bid = blockIdx.x;
    const int m = bid & 15, hb = bid >> 4;
    const int b0 = m * 16;
    const int gate = wid >> 1, half = wid & 1;
    const int jb = gate * 512 + hb * 32 + half * 16;

    // --- persistent B fragments: inline-asm loads -> cannot be rematerialized ---
    half8 bhhH[16], bhhL[16], bihF[8];
    {
        const int bcol = jb + (lane & 15);
        const int krow = (lane >> 4) * 8;
        const _Float16* ph = whhHi + (size_t)bcol * NH + krow;
        const _Float16* pl = whhLo + (size_t)bcol * NH + krow;
        const _Float16* pw = wih16 + (size_t)bcol * ND + krow;
        #pragma unroll
        for (int kk = 0; kk < 16; ++kk) {
            asm volatile("global_load_dwordx4 %0, %1, off"
                         : "=v"(bhhH[kk]) : "v"(ph + kk * 32));
            asm volatile("global_load_dwordx4 %0, %1, off"
                         : "=v"(bhhL[kk]) : "v"(pl + kk * 32));
        }
        #pragma unroll
        for (int kk = 0; kk < 8; ++kk)
            asm volatile("global_load_dwordx4 %0, %1, off"
                         : "=v"(bihF[kk]) : "v"(pw + kk * 32));
        asm volatile("s_waitcnt vmcnt(0)" ::: "memory");
        __builtin_amdgcn_sched_barrier(0);
    }

    // --- cell-phase thread mapping: one (b, h_idx) per thread ---
    const int bl = tid >> 5, hl = tid & 31;
    float bias_[4];
    #pragma unroll
    for (int g = 0; g < 4; ++g) {
        const int j = g * 512 + hb * 32 + hl;
        bias_[g] = b_ih[j] + b_hh[j];
    }
    float c = 0.f;
    float* hsOut = out_hs + (size_t)(b0 + bl) * NL * NH + hb * 32 + hl;
    unsigned int* hWr = h32 + (size_t)(b0 + bl) * NH + hb * 32 + hl;  // + buf*NB*NH

    // A-frag read geometry
    const int arow = lane & 15;
    const int aq = (lane >> 4) * 16;     // byte offset of 16B chunk within 64B k-block
    const int aswz = (arow & 7) << 4;

    // poll/stage geometry: thread -> rows r1 = tid>>6 and r1+8, 16B payload each
    const int r1 = tid >> 6;                       // 0..7
    const int tagoff = (tid & 63) * 8;             // u32 index within row (8 u32 = 16B payload)
    const int hdst = (tid * 16) ^ (r1 << 4);       // conflict-free lane-linear + swizzle
    const int wrow = tid >> 5;                     // 0..15
    const int wdst = (tid * 16) ^ ((wrow & 7) << 4);

    // ---- prologue: stage w16[t=0] into wLDS[0]; prefetch w16[t=1] ----
    {
        const _Float16* wsrc = w16 + (size_t)(b0 + wrow) * ND + (tid & 31) * 8;
        *(intx4*)(smem + 16384 + wdst) = *(const intx4*)wsrc;
    }
    intx4 wpref;
    {
        const _Float16* wsrc = w16 + ((size_t)1 * NB + b0 + wrow) * ND + (tid & 31) * 8;
        asm volatile("global_load_dwordx4 %0, %1, off" : "=v"(wpref) : "v"(wsrc));
    }
    __syncthreads();

    #pragma unroll 1
    for (int t = 0; t < NL; ++t) {
        const int cur = t & 1, nxt = (t + 1) & 1;

        // ---- (1) issue poll loads for h_t (no wait yet) ----
        intx4 q0, q1, q2, q3;
        const unsigned int* p1 =
            h32 + (size_t)cur * NB * NH + (size_t)(b0 + r1) * NH + tagoff;
        const unsigned int* p2 = p1 + (size_t)8 * NH;
        if (t > 0) {
            asm volatile(
                "global_load_dwordx4 %0, %4, off sc0 sc1\n\t"
                "global_load_dwordx4 %1, %4, off offset:16 sc0 sc1\n\t"
                "global_load_dwordx4 %2, %5, off sc0 sc1\n\t"
                "global_load_dwordx4 %3, %5, off offset:16 sc0 sc1"
                : "=v"(q0), "=v"(q1), "=v"(q2), "=v"(q3)
                : "v"(p1), "v"(p2) : "memory");
        }

        // ---- (2) accC = w @ W_ih^T from wLDS[cur] (independent of h_t) ----
        floatx4 accC = {0.f, 0.f, 0.f, 0.f};
        #pragma unroll
        for (int kk = 0; kk < 8; ++kk) {
            const int waddr = 16384 + 8192 * cur + (((arow << 9) + (kk << 6) + aq) ^ aswz);
            const half8 a = *(const half8*)(smem + waddr);
            accC = __builtin_amdgcn_mfma_f32_16x16x32_f16(a, bihF[kk], accC, 0, 0, 0);
        }

        // ---- (3) wait + tag-check + (re-poll if stale) + stage to LDS ----
        if (t > 0) {
            asm volatile("s_waitcnt vmcnt(0)" ::: "memory");
            __builtin_amdgcn_sched_barrier(0);
            const unsigned int et = (unsigned int)t;
            bool ok = true;
            #pragma unroll
            for (int i = 0; i < 4; ++i) {
                ok &= (((unsigned int)q0[i]) >> 16) == et;
                ok &= (((unsigned int)q1[i]) >> 16) == et;
                ok &= (((unsigned int)q2[i]) >> 16) == et;
                ok &= (((unsigned int)q3[i]) >> 16) == et;
            }
            while (!ok) {
                asm volatile(
                    "global_load_dwordx4 %0, %4, off sc0 sc1\n\t"
                    "global_load_dwordx4 %1, %4, off offset:16 sc0 sc1\n\t"
                    "global_load_dwordx4 %2, %5, off sc0 sc1\n\t"
                    "global_load_dwordx4 %3, %5, off offset:16 sc0 sc1\n\t"
                    "s_waitcnt vmcnt(0)"
                    : "=v"(q0), "=v"(q1), "=v"(q2), "=v"(q3)
                    : "v"(p1), "v"(p2) : "memory");
                ok = true;
                #pragma unroll
                for (int i = 0; i < 4; ++i) {
                    ok &= (((unsigned int)q0[i]) >> 16) == et;
                    ok &= (((unsigned int)q1[i]) >> 16) == et;
                    ok &= (((unsigned int)q2[i]) >> 16) == et;
                    ok &= (((unsigned int)q3[i]) >> 16) == et;
                }
            }
            intx4 d0, d1;
            d0[0] = (q0[0] & 0xffff) | (q0[1] << 16);
            d0[1] = (q0[2] & 0xffff) | (q0[3] << 16);
            d0[2] = (q1[0] & 0xffff) | (q1[1] << 16);
            d0[3] = (q1[2] & 0xffff) | (q1[3] << 16);
            d1[0] = (q2[0] & 0xffff) | (q2[1] << 16);
            d1[1] = (q2[2] & 0xffff) | (q2[3] << 16);
            d1[2] = (q3[0] & 0xffff) | (q3[1] << 16);
            d1[3] = (q3[2] & 0xffff) | (q3[3] << 16);
            *(intx4*)(smem + hdst) = d0;
            *(intx4*)(smem + 8192 + hdst) = d1;
        } else {
            const intx4 z = {0, 0, 0, 0};
            *(intx4*)(smem + hdst) = z;
            *(intx4*)(smem + 8192 + hdst) = z;
        }
        // stage w prefetch (loaded last iteration; landed under the poll wait)
        *(intx4*)(smem + 16384 + 8192 * nxt + wdst) = wpref;
        // issue next w prefetch (w16[t+2]); lands during GEMM+cell
        {
            const int tp = (t + 2 < NL) ? t + 2 : NL - 1;
            const _Float16* wsrc =
                w16 + ((size_t)tp * NB + b0 + wrow) * ND + (tid & 31) * 8;
            asm volatile("global_load_dwordx4 %0, %1, off" : "=v"(wpref) : "v"(wsrc));
        }
        __syncthreads();

        // ---- (4) h GEMM: K=512 with hi/lo split weights ----
        floatx4 accA = {0.f, 0.f, 0.f, 0.f};
        floatx4 accB = {0.f, 0.f, 0.f, 0.f};
        #pragma unroll
        for (int kk = 0; kk < 16; ++kk) {
            const int aaddr = ((arow << 10) + (kk << 6) + aq) ^ aswz;
            const half8 a = *(const half8*)(smem + aaddr);
            accA = __builtin_amdgcn_mfma_f32_16x16x32_f16(a, bhhH[kk], accA, 0, 0, 0);
            accB = __builtin_amdgcn_mfma_f32_16x16x32_f16(a, bhhL[kk], accB, 0, 0, 0);
        }
        const floatx4 f = (accA + accB) + accC;

        // ---- (5) exchange acc tiles through LDS (stride 17: conflict-free) ----
        {
            float* accL = (float*)(smem + 32768);
            const int colw = lane & 15, rowq = (lane >> 4) * 4;
            #pragma unroll
            for (int r = 0; r < 4; ++r)
                accL[wid * 272 + (rowq + r) * 17 + colw] = f[r];
        }
        __syncthreads();

        // ---- (6) LSTM cell (one (b, h_idx) per thread; c in register) ----
        float h2;
        {
            const float* accL = (const float*)(smem + 32768);
            const int hq = hl >> 4, cidx = hl & 15;
            const int off = bl * 17 + cidx;
            const float pi = accL[(0 + hq) * 272 + off] + bias_[0];
            const float pf = accL[(2 + hq) * 272 + off] + bias_[1];
            const float pg = accL[(4 + hq) * 272 + off] + bias_[2];
            const float po = accL[(6 + hq) * 272 + off] + bias_[3];
            const float si = 1.f / (1.f + __expf(-pi));
            const float sf = 1.f / (1.f + __expf(-pf));
            const float so = 1.f / (1.f + __expf(-po));
            float e2 = __expf(-2.f * fabsf(pg));
            float tg = (1.f - e2) / (1.f + e2);
            tg = (pg < 0.f) ? -tg : tg;
            c = sf * c + si * tg;
            float e2c = __expf(-2.f * fabsf(c));
            float tc = (1.f - e2c) / (1.f + e2c);
            tc = (c < 0.f) ? -tc : tc;
            h2 = so * tc;
            // epoch-tagged h store (fire-and-forget, device-visible)
            const _Float16 hh = (_Float16)h2;
            const unsigned int hv =
                ((unsigned int)(t + 1) << 16) |
                (unsigned int)__builtin_bit_cast(unsigned short, hh);
            const void* hp = hWr + (size_t)nxt * NB * NH;
            asm volatile("global_store_dword %0, %1, off sc0 sc1"
                         :: "v"(hp), "v"(hv) : "memory");
        }
        hsOut[(size_t)t * NH] = h2;   // fire-and-forget HBM store
    }
}

extern "C" void kernel_launch(void* const* d_in, const int* in_sizes, int n_in,
                              void* d_out, int out_size, void* d_ws, size_t ws_size,
                              hipStream_t stream) {
    const float* x     = (const float*)d_in[0];
    const float* Wattn = (const float*)d_in[1];
    // d_in[2] = b_attn : provably unused (softmax shift invariance)
    const float* Wih   = (const float*)d_in[3];
    const float* Whh   = (const float*)d_in[4];
    const float* bih   = (const float*)d_in[5];
    const float* bhh   = (const float*)d_in[6];

    float* ws_out = (float*)d_out;                                 // [B][L][D]
    float* hs_out = ws_out + (size_t)NB * NL * ND;                 // [B][L][H]

    char* ws = (char*)d_ws;
    float*    attn  = (float*)(ws + 4096);                         // 256 KB
    float*    xproj = (float*)(ws + 4096 + 262144);                // 256 KB
    unsigned int* h32 = (unsigned int*)(ws + 1048576);             // 2 x 512 KB tagged
    _Float16* whhHi = (_Float16*)(ws + 2097152);                   // 2 MB
    _Float16* whhLo = (_Float16*)(ws + 2097152 + 2097152);         // 2 MB
    _Float16* wih16 = (_Float16*)(ws + 6291456);                   // 1 MB
    _Float16* w16   = (_Float16*)(ws + 8388608);                   // 33.5 MB

    // Clear epoch tags: prevents stale tag collision across timed replays.
    hipMemsetAsync(h32, 0, (size_t)2 * NB * NH * 4, stream);

    k_xproj  <<<16384, 256, 0, stream>>>(x, Wattn, xproj);
    k_softmax<<<256,   256, 0, stream>>>(xproj, attn);
    k_trans  <<<4096,  256, 0, stream>>>(x, attn, ws_out, w16);
    k_wsplit <<<4096,  256, 0, stream>>>(Whh, Wih, whhHi, whhLo, wih16);
    k_recur  <<<256,   512, 0, stream>>>(whhHi, whhLo, wih16, w16, bih, bhh,
                                         h32, hs_out);
}

// Round 7
// 994.876 us; speedup vs baseline: 1.0006x; 1.0002x over previous
//
#include <hip/hip_runtime.h>
#include <hip/hip_fp16.h>

typedef _Float16 half8 __attribute__((ext_vector_type(8)));
typedef float floatx4 __attribute__((ext_vector_type(4)));
typedef int intx4 __attribute__((ext_vector_type(4)));

#define NB 256   // batch
#define ND 256   // D
#define NL 256   // L (time)
#define NH 512   // H

// ---------------- Kernel 1: x_proj[b,d] = sum_l x[b,d,l] * Wx[l] ----------------
__global__ void k_xproj(const float* __restrict__ x, const float* __restrict__ Wattn,
                        float* __restrict__ xproj) {
    __shared__ float wx[NL];
    const int tid = threadIdx.x;
    wx[tid] = Wattn[2 * NH + tid];   // blockDim = 256 == NL
    __syncthreads();
    const int wid = tid >> 6, lane = tid & 63;
    const int row = blockIdx.x * 4 + wid;          // row = b*ND + d, 65536 rows
    const float4 v = ((const float4*)(x + (size_t)row * NL))[lane];
    float s = v.x * wx[lane * 4] + v.y * wx[lane * 4 + 1] +
              v.z * wx[lane * 4 + 2] + v.w * wx[lane * 4 + 3];
    #pragma unroll
    for (int off = 32; off; off >>= 1) s += __shfl_down(s, off);
    if (lane == 0) xproj[row] = s;
}

// ---------------- Kernel 2: attn[b,:] = softmax(x_proj[b,:]) ----------------
__global__ void k_softmax(const float* __restrict__ xproj, float* __restrict__ attn) {
    const int b = blockIdx.x, tid = threadIdx.x;
    __shared__ float red[8];
    float v = xproj[b * ND + tid];
    float m = v;
    #pragma unroll
    for (int off = 32; off; off >>= 1) m = fmaxf(m, __shfl_down(m, off));
    const int wid = tid >> 6, lane = tid & 63;
    if (lane == 0) red[wid] = m;
    __syncthreads();
    if (tid == 0) {
        float mm = fmaxf(fmaxf(red[0], red[1]), fmaxf(red[2], red[3]));
        red[4] = mm;
    }
    __syncthreads();
    const float e = expf(v - red[4]);
    float s = e;
    #pragma unroll
    for (int off = 32; off; off >>= 1) s += __shfl_down(s, off);
    if (lane == 0) red[wid] = s;
    __syncthreads();
    if (tid == 0) red[5] = red[0] + red[1] + red[2] + red[3];
    __syncthreads();
    attn[b * ND + tid] = e / red[5];
}

// ---- Kernel 3: ws[b,t,d] = attn[b,d]*x[b,d,t] (fp32 out) ; w16[t,b,d] = fp16(same) ----
__global__ void k_trans(const float* __restrict__ x, const float* __restrict__ attn,
                        float* __restrict__ ws_out, _Float16* __restrict__ w16) {
    __shared__ float tile[64][65];
    const int bid = blockIdx.x;
    const int b = bid >> 4, ti = (bid >> 2) & 3, tj = bid & 3;
    const int tx = threadIdx.x & 63, ty = threadIdx.x >> 6;
    const int d0 = ti * 64, l0 = tj * 64;
    const float* xb = x + ((size_t)b * ND + d0) * NL + l0;
    #pragma unroll
    for (int r = ty; r < 64; r += 4) tile[r][tx] = xb[(size_t)r * NL + tx];
    __syncthreads();
    const float af = attn[b * ND + d0 + tx];
    #pragma unroll
    for (int r = ty; r < 64; r += 4) {
        const int tt = l0 + r;
        const float val = af * tile[tx][r];
        ws_out[((size_t)b * NL + tt) * ND + d0 + tx] = val;
        w16[((size_t)tt * NB + b) * ND + d0 + tx] = (_Float16)val;
    }
}

// ---------------- Kernel 4: weight conversion (hi/lo split for W_hh) ----------------
__global__ void k_wsplit(const float* __restrict__ Whh, const float* __restrict__ Wih,
                         _Float16* __restrict__ hi, _Float16* __restrict__ lo,
                         _Float16* __restrict__ wih16) {
    const int idx = blockIdx.x * 256 + threadIdx.x;   // 4096*256 = 1048576 = 4H*H
    const float w = Whh[idx];
    const _Float16 h = (_Float16)w;
    hi[idx] = h;
    lo[idx] = (_Float16)(w - (float)h);
    if (idx < 4 * NH * ND) wih16[idx] = (_Float16)Wih[idx];
}

// ---------------- Kernel 5: persistent LSTM recurrence ----------------
// grid = 256 wgs x 512 thr. wg (m = bid&15, hb = bid>>4):
//   rows b in [16m, 16m+16), gate cols j = g*512 + hb*32 + [0,32) for g=0..3
// group = 16 wgs sharing m. Epoch-tagged h exchange (see R4 notes).
// R7 change: amdgpu_waves_per_eu(2,2). Both (512,2) and bare (512) resolve
// to min 4 waves/EU -> 128-VGPR cap, which spilled the 160 fragment VGPRs
// (R5/R6) or forced per-step L2 refetch (R2/R4). min=2 waves/EU = our true
// occupancy (one 8-wave wg per CU) -> 256-VGPR cap -> fragments resident.
__attribute__((amdgpu_waves_per_eu(2, 2)))
__launch_bounds__(512)
__global__ void k_recur(const _Float16* __restrict__ whhHi, const _Float16* __restrict__ whhLo,
                        const _Float16* __restrict__ wih16, const _Float16* __restrict__ w16,
                        const float* __restrict__ b_ih, const float* __restrict__ b_hh,
                        unsigned int* __restrict__ h32,   // [2][NB][NH] epoch-tagged
                        float* __restrict__ out_hs)       // [NB][NL][NH]
{
    __shared__ char smem[41472];
    // [0,16384)      : hLDS  [16 rows][1024B] fp16, XOR-swizzled (row&7)<<4
    // [16384,32768)  : wLDS  2 x [16 rows][512B] fp16, same swizzle
    // [32768,41472)  : accL  float[8][16][17]
    const int tid = threadIdx.x;
    const int wid = tid >> 6, lane = tid & 63;
    const int bid = blockIdx.x;
    const int m = bid & 15, hb = bid >> 4;
    const int b0 = m * 16;
    const int gate = wid >> 1, half = wid & 1;
    const int jb = gate * 512 + hb * 32 + half * 16;

    // --- persistent B fragments: inline-asm loads -> cannot be rematerialized ---
    half8 bhhH[16], bhhL[16], bihF[8];
    {
        const int bcol = jb + (lane & 15);
        const int krow = (lane >> 4) * 8;
        const _Float16* ph = whhHi + (size_t)bcol * NH + krow;
        const _Float16* pl = whhLo + (size_t)bcol * NH + krow;
        const _Float16* pw = wih16 + (size_t)bcol * ND + krow;
        #pragma unroll
        for (int kk = 0; kk < 16; ++kk) {
            asm volatile("global_load_dwordx4 %0, %1, off"
                         : "=v"(bhhH[kk]) : "v"(ph + kk * 32));
            asm volatile("global_load_dwordx4 %0, %1, off"
                         : "=v"(bhhL[kk]) : "v"(pl + kk * 32));
        }
        #pragma unroll
        for (int kk = 0; kk < 8; ++kk)
            asm volatile("global_load_dwordx4 %0, %1, off"
                         : "=v"(bihF[kk]) : "v"(pw + kk * 32));
        asm volatile("s_waitcnt vmcnt(0)" ::: "memory");
        __builtin_amdgcn_sched_barrier(0);
    }

    // --- cell-phase thread mapping: one (b, h_idx) per thread ---
    const int bl = tid >> 5, hl = tid & 31;
    float bias_[4];
    #pragma unroll
    for (int g = 0; g < 4; ++g) {
        const int j = g * 512 + hb * 32 + hl;
        bias_[g] = b_ih[j] + b_hh[j];
    }
    float c = 0.f;
    float* hsOut = out_hs + (size_t)(b0 + bl) * NL * NH + hb * 32 + hl;
    unsigned int* hWr = h32 + (size_t)(b0 + bl) * NH + hb * 32 + hl;  // + buf*NB*NH

    // A-frag read geometry
    const int arow = lane & 15;
    const int aq = (lane >> 4) * 16;     // byte offset of 16B chunk within 64B k-block
    const int aswz = (arow & 7) << 4;

    // poll/stage geometry: thread -> rows r1 = tid>>6 and r1+8, 16B payload each
    const int r1 = tid >> 6;                       // 0..7
    const int tagoff = (tid & 63) * 8;             // u32 index within row (8 u32 = 16B payload)
    const int hdst = (tid * 16) ^ (r1 << 4);       // conflict-free lane-linear + swizzle
    const int wrow = tid >> 5;                     // 0..15
    const int wdst = (tid * 16) ^ ((wrow & 7) << 4);

    // ---- prologue: stage w16[t=0] into wLDS[0]; prefetch w16[t=1] ----
    {
        const _Float16* wsrc = w16 + (size_t)(b0 + wrow) * ND + (tid & 31) * 8;
        *(intx4*)(smem + 16384 + wdst) = *(const intx4*)wsrc;
    }
    intx4 wpref;
    {
        const _Float16* wsrc = w16 + ((size_t)1 * NB + b0 + wrow) * ND + (tid & 31) * 8;
        asm volatile("global_load_dwordx4 %0, %1, off" : "=v"(wpref) : "v"(wsrc));
    }
    __syncthreads();

    #pragma unroll 1
    for (int t = 0; t < NL; ++t) {
        const int cur = t & 1, nxt = (t + 1) & 1;

        // ---- (1) issue poll loads for h_t (no wait yet) ----
        intx4 q0, q1, q2, q3;
        const unsigned int* p1 =
            h32 + (size_t)cur * NB * NH + (size_t)(b0 + r1) * NH + tagoff;
        const unsigned int* p2 = p1 + (size_t)8 * NH;
        if (t > 0) {
            asm volatile(
                "global_load_dwordx4 %0, %4, off sc0 sc1\n\t"
                "global_load_dwordx4 %1, %4, off offset:16 sc0 sc1\n\t"
                "global_load_dwordx4 %2, %5, off sc0 sc1\n\t"
                "global_load_dwordx4 %3, %5, off offset:16 sc0 sc1"
                : "=v"(q0), "=v"(q1), "=v"(q2), "=v"(q3)
                : "v"(p1), "v"(p2) : "memory");
        }

        // ---- (2) accC = w @ W_ih^T from wLDS[cur] (independent of h_t) ----
        floatx4 accC = {0.f, 0.f, 0.f, 0.f};
        #pragma unroll
        for (int kk = 0; kk < 8; ++kk) {
            const int waddr = 16384 + 8192 * cur + (((arow << 9) + (kk << 6) + aq) ^ aswz);
            const half8 a = *(const half8*)(smem + waddr);
            accC = __builtin_amdgcn_mfma_f32_16x16x32_f16(a, bihF[kk], accC, 0, 0, 0);
        }

        // ---- (3) wait + tag-check + (re-poll if stale) + stage to LDS ----
        if (t > 0) {
            asm volatile("s_waitcnt vmcnt(0)" ::: "memory");
            __builtin_amdgcn_sched_barrier(0);
            const unsigned int et = (unsigned int)t;
            bool ok = true;
            #pragma unroll
            for (int i = 0; i < 4; ++i) {
                ok &= (((unsigned int)q0[i]) >> 16) == et;
                ok &= (((unsigned int)q1[i]) >> 16) == et;
                ok &= (((unsigned int)q2[i]) >> 16) == et;
                ok &= (((unsigned int)q3[i]) >> 16) == et;
            }
            while (!ok) {
                asm volatile(
                    "global_load_dwordx4 %0, %4, off sc0 sc1\n\t"
                    "global_load_dwordx4 %1, %4, off offset:16 sc0 sc1\n\t"
                    "global_load_dwordx4 %2, %5, off sc0 sc1\n\t"
                    "global_load_dwordx4 %3, %5, off offset:16 sc0 sc1\n\t"
                    "s_waitcnt vmcnt(0)"
                    : "=v"(q0), "=v"(q1), "=v"(q2), "=v"(q3)
                    : "v"(p1), "v"(p2) : "memory");
                ok = true;
                #pragma unroll
                for (int i = 0; i < 4; ++i) {
                    ok &= (((unsigned int)q0[i]) >> 16) == et;
                    ok &= (((unsigned int)q1[i]) >> 16) == et;
                    ok &= (((unsigned int)q2[i]) >> 16) == et;
                    ok &= (((unsigned int)q3[i]) >> 16) == et;
                }
            }
            intx4 d0, d1;
            d0[0] = (q0[0] & 0xffff) | (q0[1] << 16);
            d0[1] = (q0[2] & 0xffff) | (q0[3] << 16);
            d0[2] = (q1[0] & 0xffff) | (q1[1] << 16);
            d0[3] = (q1[2] & 0xffff) | (q1[3] << 16);
            d1[0] = (q2[0] & 0xffff) | (q2[1] << 16);
            d1[1] = (q2[2] & 0xffff) | (q2[3] << 16);
            d1[2] = (q3[0] & 0xffff) | (q3[1] << 16);
            d1[3] = (q3[2] & 0xffff) | (q3[3] << 16);
            *(intx4*)(smem + hdst) = d0;
            *(intx4*)(smem + 8192 + hdst) = d1;
        } else {
            const intx4 z = {0, 0, 0, 0};
            *(intx4*)(smem + hdst) = z;
            *(intx4*)(smem + 8192 + hdst) = z;
        }
        // stage w prefetch (loaded last iteration; landed under the poll wait)
        *(intx4*)(smem + 16384 + 8192 * nxt + wdst) = wpref;
        // issue next w prefetch (w16[t+2]); lands during GEMM+cell
        {
            const int tp = (t + 2 < NL) ? t + 2 : NL - 1;
            const _Float16* wsrc =
                w16 + ((size_t)tp * NB + b0 + wrow) * ND + (tid & 31) * 8;
            asm volatile("global_load_dwordx4 %0, %1, off" : "=v"(wpref) : "v"(wsrc));
        }
        __syncthreads();

        // ---- (4) h GEMM: K=512 with hi/lo split weights ----
        floatx4 accA = {0.f, 0.f, 0.f, 0.f};
        floatx4 accB = {0.f, 0.f, 0.f, 0.f};
        #pragma unroll
        for (int kk = 0; kk < 16; ++kk) {
            const int aaddr = ((arow << 10) + (kk << 6) + aq) ^ aswz;
            const half8 a = *(const half8*)(smem + aaddr);
            accA = __builtin_amdgcn_mfma_f32_16x16x32_f16(a, bhhH[kk], accA, 0, 0, 0);
            accB = __builtin_amdgcn_mfma_f32_16x16x32_f16(a, bhhL[kk], accB, 0, 0, 0);
        }
        const floatx4 f = (accA + accB) + accC;

        // ---- (5) exchange acc tiles through LDS (stride 17: conflict-free) ----
        {
            float* accL = (float*)(smem + 32768);
            const int colw = lane & 15, rowq = (lane >> 4) * 4;
            #pragma unroll
            for (int r = 0; r < 4; ++r)
                accL[wid * 272 + (rowq + r) * 17 + colw] = f[r];
        }
        __syncthreads();

        // ---- (6) LSTM cell (one (b, h_idx) per thread; c in register) ----
        float h2;
        {
            const float* accL = (const float*)(smem + 32768);
            const int hq = hl >> 4, cidx = hl & 15;
            const int off = bl * 17 + cidx;
            const float pi = accL[(0 + hq) * 272 + off] + bias_[0];
            const float pf = accL[(2 + hq) * 272 + off] + bias_[1];
            const float pg = accL[(4 + hq) * 272 + off] + bias_[2];
            const float po = accL[(6 + hq) * 272 + off] + bias_[3];
            const float si = 1.f / (1.f + __expf(-pi));
            const float sf = 1.f / (1.f + __expf(-pf));
            const float so = 1.f / (1.f + __expf(-po));
            float e2 = __expf(-2.f * fabsf(pg));
            float tg = (1.f - e2) / (1.f + e2);
            tg = (pg < 0.f) ? -tg : tg;
            c = sf * c + si * tg;
            float e2c = __expf(-2.f * fabsf(c));
            float tc = (1.f - e2c) / (1.f + e2c);
            tc = (c < 0.f) ? -tc : tc;
            h2 = so * tc;
            // epoch-tagged h store (fire-and-forget, device-visible)
            const _Float16 hh = (_Float16)h2;
            const unsigned int hv =
                ((unsigned int)(t + 1) << 16) |
                (unsigned int)__builtin_bit_cast(unsigned short, hh);
            const void* hp = hWr + (size_t)nxt * NB * NH;
            asm volatile("global_store_dword %0, %1, off sc0 sc1"
                         :: "v"(hp), "v"(hv) : "memory");
        }
        hsOut[(size_t)t * NH] = h2;   // fire-and-forget HBM store
    }
}

extern "C" void kernel_launch(void* const* d_in, const int* in_sizes, int n_in,
                              void* d_out, int out_size, void* d_ws, size_t ws_size,
                              hipStream_t stream) {
    const float* x     = (const float*)d_in[0];
    const float* Wattn = (const float*)d_in[1];
    // d_in[2] = b_attn : provably unused (softmax shift invariance)
    const float* Wih   = (const float*)d_in[3];
    const float* Whh   = (const float*)d_in[4];
    const float* bih   = (const float*)d_in[5];
    const float* bhh   = (const float*)d_in[6];

    float* ws_out = (float*)d_out;                                 // [B][L][D]
    float* hs_out = ws_out + (size_t)NB * NL * ND;                 // [B][L][H]

    char* ws = (char*)d_ws;
    float*    attn  = (float*)(ws + 4096);                         // 256 KB
    float*    xproj = (float*)(ws + 4096 + 262144);                // 256 KB
    unsigned int* h32 = (unsigned int*)(ws + 1048576);             // 2 x 512 KB tagged
    _Float16* whhHi = (_Float16*)(ws + 2097152);                   // 2 MB
    _Float16* whhLo = (_Float16*)(ws + 2097152 + 2097152);         // 2 MB
    _Float16* wih16 = (_Float16*)(ws + 6291456);                   // 1 MB
    _Float16* w16   = (_Float16*)(ws + 8388608);                   // 33.5 MB

    // Clear epoch tags: prevents stale tag collision across timed replays.
    hipMemsetAsync(h32, 0, (size_t)2 * NB * NH * 4, stream);

    k_xproj  <<<16384, 256, 0, stream>>>(x, Wattn, xproj);
    k_softmax<<<256,   256, 0, stream>>>(xproj, attn);
    k_trans  <<<4096,  256, 0, stream>>>(x, attn, ws_out, w16);
    k_wsplit <<<4096,  256, 0, stream>>>(Whh, Wih, whhHi, whhLo, wih16);
    k_recur  <<<256,   512, 0, stream>>>(whhHi, whhLo, wih16, w16, bih, bhh,
                                         h32, hs_out);
}

// Round 8
// 992.943 us; speedup vs baseline: 1.0026x; 1.0019x over previous
//
#include <hip/hip_runtime.h>
#include <hip/hip_fp16.h>

typedef _Float16 half8 __attribute__((ext_vector_type(8)));
typedef float floatx4 __attribute__((ext_vector_type(4)));
typedef int intx4 __attribute__((ext_vector_type(4)));

#define NB 256   // batch
#define ND 256   // D
#define NL 256   // L (time)
#define NH 512   // H

// ---------------- Kernel 1: x_proj[b,d] = sum_l x[b,d,l] * Wx[l] ----------------
__global__ void k_xproj(const float* __restrict__ x, const float* __restrict__ Wattn,
                        float* __restrict__ xproj) {
    __shared__ float wx[NL];
    const int tid = threadIdx.x;
    wx[tid] = Wattn[2 * NH + tid];   // blockDim = 256 == NL
    __syncthreads();
    const int wid = tid >> 6, lane = tid & 63;
    const int row = blockIdx.x * 4 + wid;          // row = b*ND + d, 65536 rows
    const float4 v = ((const float4*)(x + (size_t)row * NL))[lane];
    float s = v.x * wx[lane * 4] + v.y * wx[lane * 4 + 1] +
              v.z * wx[lane * 4 + 2] + v.w * wx[lane * 4 + 3];
    #pragma unroll
    for (int off = 32; off; off >>= 1) s += __shfl_down(s, off);
    if (lane == 0) xproj[row] = s;
}

// ---------------- Kernel 2: attn[b,:] = softmax(x_proj[b,:]) ----------------
__global__ void k_softmax(const float* __restrict__ xproj, float* __restrict__ attn) {
    const int b = blockIdx.x, tid = threadIdx.x;
    __shared__ float red[8];
    float v = xproj[b * ND + tid];
    float m = v;
    #pragma unroll
    for (int off = 32; off; off >>= 1) m = fmaxf(m, __shfl_down(m, off));
    const int wid = tid >> 6, lane = tid & 63;
    if (lane == 0) red[wid] = m;
    __syncthreads();
    if (tid == 0) {
        float mm = fmaxf(fmaxf(red[0], red[1]), fmaxf(red[2], red[3]));
        red[4] = mm;
    }
    __syncthreads();
    const float e = expf(v - red[4]);
    float s = e;
    #pragma unroll
    for (int off = 32; off; off >>= 1) s += __shfl_down(s, off);
    if (lane == 0) red[wid] = s;
    __syncthreads();
    if (tid == 0) red[5] = red[0] + red[1] + red[2] + red[3];
    __syncthreads();
    attn[b * ND + tid] = e / red[5];
}

// ---- Kernel 3: ws[b,t,d] = attn[b,d]*x[b,d,t] (fp32 out) ; w16[t,b,d] = fp16(same) ----
__global__ void k_trans(const float* __restrict__ x, const float* __restrict__ attn,
                        float* __restrict__ ws_out, _Float16* __restrict__ w16) {
    __shared__ float tile[64][65];
    const int bid = blockIdx.x;
    const int b = bid >> 4, ti = (bid >> 2) & 3, tj = bid & 3;
    const int tx = threadIdx.x & 63, ty = threadIdx.x >> 6;
    const int d0 = ti * 64, l0 = tj * 64;
    const float* xb = x + ((size_t)b * ND + d0) * NL + l0;
    #pragma unroll
    for (int r = ty; r < 64; r += 4) tile[r][tx] = xb[(size_t)r * NL + tx];
    __syncthreads();
    const float af = attn[b * ND + d0 + tx];
    #pragma unroll
    for (int r = ty; r < 64; r += 4) {
        const int tt = l0 + r;
        const float val = af * tile[tx][r];
        ws_out[((size_t)b * NL + tt) * ND + d0 + tx] = val;
        w16[((size_t)tt * NB + b) * ND + d0 + tx] = (_Float16)val;
    }
}

// ---------------- Kernel 4: weight conversion (hi/lo split for W_hh) ----------------
__global__ void k_wsplit(const float* __restrict__ Whh, const float* __restrict__ Wih,
                         _Float16* __restrict__ hi, _Float16* __restrict__ lo,
                         _Float16* __restrict__ wih16) {
    const int idx = blockIdx.x * 256 + threadIdx.x;   // 4096*256 = 1048576 = 4H*H
    const float w = Whh[idx];
    const _Float16 h = (_Float16)w;
    hi[idx] = h;
    lo[idx] = (_Float16)(w - (float)h);
    if (idx < 4 * NH * ND) wih16[idx] = (_Float16)Wih[idx];
}

// ---------------- Kernel 5: persistent LSTM recurrence ----------------
// grid = 256 wgs x 512 thr. wg (m = bid&15, hb = bid>>4):
//   rows b in [16m, 16m+16), gate cols j = g*512 + hb*32 + [0,32) for g=0..3
// group = 16 wgs sharing m. Epoch-tagged h exchange (see R4 notes).
// R8 change: __launch_bounds__(512, 1). Toolchain evidence (R1-R7) says the
// 2nd arg is CUDA-style min BLOCKS/CU, lowered to waves-per-eu = blocks*8/4:
//   (512,2) -> 4 waves/EU -> 128-VGPR cap (R1-R5: refetch/spill)
//   (512)   -> default 4  -> 128 cap (R6)
//   attribute override    -> ignored (R7)
// (512,1) -> 2 waves/EU -> 256-VGPR cap -> the 160 fragment VGPRs resident.
__launch_bounds__(512, 1)
__global__ void k_recur(const _Float16* __restrict__ whhHi, const _Float16* __restrict__ whhLo,
                        const _Float16* __restrict__ wih16, const _Float16* __restrict__ w16,
                        const float* __restrict__ b_ih, const float* __restrict__ b_hh,
                        unsigned int* __restrict__ h32,   // [2][NB][NH] epoch-tagged
                        float* __restrict__ out_hs)       // [NB][NL][NH]
{
    __shared__ char smem[41472];
    // [0,16384)      : hLDS  [16 rows][1024B] fp16, XOR-swizzled (row&7)<<4
    // [16384,32768)  : wLDS  2 x [16 rows][512B] fp16, same swizzle
    // [32768,41472)  : accL  float[8][16][17]
    const int tid = threadIdx.x;
    const int wid = tid >> 6, lane = tid & 63;
    const int bid = blockIdx.x;
    const int m = bid & 15, hb = bid >> 4;
    const int b0 = m * 16;
    const int gate = wid >> 1, half = wid & 1;
    const int jb = gate * 512 + hb * 32 + half * 16;

    // --- persistent B fragments: inline-asm loads -> cannot be rematerialized ---
    half8 bhhH[16], bhhL[16], bihF[8];
    {
        const int bcol = jb + (lane & 15);
        const int krow = (lane >> 4) * 8;
        const _Float16* ph = whhHi + (size_t)bcol * NH + krow;
        const _Float16* pl = whhLo + (size_t)bcol * NH + krow;
        const _Float16* pw = wih16 + (size_t)bcol * ND + krow;
        #pragma unroll
        for (int kk = 0; kk < 16; ++kk) {
            asm volatile("global_load_dwordx4 %0, %1, off"
                         : "=v"(bhhH[kk]) : "v"(ph + kk * 32));
            asm volatile("global_load_dwordx4 %0, %1, off"
                         : "=v"(bhhL[kk]) : "v"(pl + kk * 32));
        }
        #pragma unroll
        for (int kk = 0; kk < 8; ++kk)
            asm volatile("global_load_dwordx4 %0, %1, off"
                         : "=v"(bihF[kk]) : "v"(pw + kk * 32));
        asm volatile("s_waitcnt vmcnt(0)" ::: "memory");
        __builtin_amdgcn_sched_barrier(0);
    }

    // --- cell-phase thread mapping: one (b, h_idx) per thread ---
    const int bl = tid >> 5, hl = tid & 31;
    float bias_[4];
    #pragma unroll
    for (int g = 0; g < 4; ++g) {
        const int j = g * 512 + hb * 32 + hl;
        bias_[g] = b_ih[j] + b_hh[j];
    }
    float c = 0.f;
    float* hsOut = out_hs + (size_t)(b0 + bl) * NL * NH + hb * 32 + hl;
    unsigned int* hWr = h32 + (size_t)(b0 + bl) * NH + hb * 32 + hl;  // + buf*NB*NH

    // A-frag read geometry
    const int arow = lane & 15;
    const int aq = (lane >> 4) * 16;     // byte offset of 16B chunk within 64B k-block
    const int aswz = (arow & 7) << 4;

    // poll/stage geometry: thread -> rows r1 = tid>>6 and r1+8, 16B payload each
    const int r1 = tid >> 6;                       // 0..7
    const int tagoff = (tid & 63) * 8;             // u32 index within row (8 u32 = 16B payload)
    const int hdst = (tid * 16) ^ (r1 << 4);       // conflict-free lane-linear + swizzle
    const int wrow = tid >> 5;                     // 0..15
    const int wdst = (tid * 16) ^ ((wrow & 7) << 4);

    // ---- prologue: stage w16[t=0] into wLDS[0]; prefetch w16[t=1] ----
    {
        const _Float16* wsrc = w16 + (size_t)(b0 + wrow) * ND + (tid & 31) * 8;
        *(intx4*)(smem + 16384 + wdst) = *(const intx4*)wsrc;
    }
    intx4 wpref;
    {
        const _Float16* wsrc = w16 + ((size_t)1 * NB + b0 + wrow) * ND + (tid & 31) * 8;
        asm volatile("global_load_dwordx4 %0, %1, off" : "=v"(wpref) : "v"(wsrc));
    }
    __syncthreads();

    #pragma unroll 1
    for (int t = 0; t < NL; ++t) {
        const int cur = t & 1, nxt = (t + 1) & 1;

        // ---- (1) issue poll loads for h_t (no wait yet) ----
        intx4 q0, q1, q2, q3;
        const unsigned int* p1 =
            h32 + (size_t)cur * NB * NH + (size_t)(b0 + r1) * NH + tagoff;
        const unsigned int* p2 = p1 + (size_t)8 * NH;
        if (t > 0) {
            asm volatile(
                "global_load_dwordx4 %0, %4, off sc0 sc1\n\t"
                "global_load_dwordx4 %1, %4, off offset:16 sc0 sc1\n\t"
                "global_load_dwordx4 %2, %5, off sc0 sc1\n\t"
                "global_load_dwordx4 %3, %5, off offset:16 sc0 sc1"
                : "=v"(q0), "=v"(q1), "=v"(q2), "=v"(q3)
                : "v"(p1), "v"(p2) : "memory");
        }

        // ---- (2) accC = w @ W_ih^T from wLDS[cur] (independent of h_t) ----
        floatx4 accC = {0.f, 0.f, 0.f, 0.f};
        #pragma unroll
        for (int kk = 0; kk < 8; ++kk) {
            const int waddr = 16384 + 8192 * cur + (((arow << 9) + (kk << 6) + aq) ^ aswz);
            const half8 a = *(const half8*)(smem + waddr);
            accC = __builtin_amdgcn_mfma_f32_16x16x32_f16(a, bihF[kk], accC, 0, 0, 0);
        }

        // ---- (3) wait + tag-check + (re-poll if stale) + stage to LDS ----
        if (t > 0) {
            asm volatile("s_waitcnt vmcnt(0)" ::: "memory");
            __builtin_amdgcn_sched_barrier(0);
            const unsigned int et = (unsigned int)t;
            bool ok = true;
            #pragma unroll
            for (int i = 0; i < 4; ++i) {
                ok &= (((unsigned int)q0[i]) >> 16) == et;
                ok &= (((unsigned int)q1[i]) >> 16) == et;
                ok &= (((unsigned int)q2[i]) >> 16) == et;
                ok &= (((unsigned int)q3[i]) >> 16) == et;
            }
            while (!ok) {
                asm volatile(
                    "global_load_dwordx4 %0, %4, off sc0 sc1\n\t"
                    "global_load_dwordx4 %1, %4, off offset:16 sc0 sc1\n\t"
                    "global_load_dwordx4 %2, %5, off sc0 sc1\n\t"
                    "global_load_dwordx4 %3, %5, off offset:16 sc0 sc1\n\t"
                    "s_waitcnt vmcnt(0)"
                    : "=v"(q0), "=v"(q1), "=v"(q2), "=v"(q3)
                    : "v"(p1), "v"(p2) : "memory");
                ok = true;
                #pragma unroll
                for (int i = 0; i < 4; ++i) {
                    ok &= (((unsigned int)q0[i]) >> 16) == et;
                    ok &= (((unsigned int)q1[i]) >> 16) == et;
                    ok &= (((unsigned int)q2[i]) >> 16) == et;
                    ok &= (((unsigned int)q3[i]) >> 16) == et;
                }
            }
            intx4 d0, d1;
            d0[0] = (q0[0] & 0xffff) | (q0[1] << 16);
            d0[1] = (q0[2] & 0xffff) | (q0[3] << 16);
            d0[2] = (q1[0] & 0xffff) | (q1[1] << 16);
            d0[3] = (q1[2] & 0xffff) | (q1[3] << 16);
            d1[0] = (q2[0] & 0xffff) | (q2[1] << 16);
            d1[1] = (q2[2] & 0xffff) | (q2[3] << 16);
            d1[2] = (q3[0] & 0xffff) | (q3[1] << 16);
            d1[3] = (q3[2] & 0xffff) | (q3[3] << 16);
            *(intx4*)(smem + hdst) = d0;
            *(intx4*)(smem + 8192 + hdst) = d1;
        } else {
            const intx4 z = {0, 0, 0, 0};
            *(intx4*)(smem + hdst) = z;
            *(intx4*)(smem + 8192 + hdst) = z;
        }
        // stage w prefetch (loaded last iteration; landed under the poll wait)
        *(intx4*)(smem + 16384 + 8192 * nxt + wdst) = wpref;
        // issue next w prefetch (w16[t+2]); lands during GEMM+cell
        {
            const int tp = (t + 2 < NL) ? t + 2 : NL - 1;
            const _Float16* wsrc =
                w16 + ((size_t)tp * NB + b0 + wrow) * ND + (tid & 31) * 8;
            asm volatile("global_load_dwordx4 %0, %1, off" : "=v"(wpref) : "v"(wsrc));
        }
        __syncthreads();

        // ---- (4) h GEMM: K=512 with hi/lo split weights ----
        floatx4 accA = {0.f, 0.f, 0.f, 0.f};
        floatx4 accB = {0.f, 0.f, 0.f, 0.f};
        #pragma unroll
        for (int kk = 0; kk < 16; ++kk) {
            const int aaddr = ((arow << 10) + (kk << 6) + aq) ^ aswz;
            const half8 a = *(const half8*)(smem + aaddr);
            accA = __builtin_amdgcn_mfma_f32_16x16x32_f16(a, bhhH[kk], accA, 0, 0, 0);
            accB = __builtin_amdgcn_mfma_f32_16x16x32_f16(a, bhhL[kk], accB, 0, 0, 0);
        }
        const floatx4 f = (accA + accB) + accC;

        // ---- (5) exchange acc tiles through LDS (stride 17: conflict-free) ----
        {
            float* accL = (float*)(smem + 32768);
            const int colw = lane & 15, rowq = (lane >> 4) * 4;
            #pragma unroll
            for (int r = 0; r < 4; ++r)
                accL[wid * 272 + (rowq + r) * 17 + colw] = f[r];
        }
        __syncthreads();

        // ---- (6) LSTM cell (one (b, h_idx) per thread; c in register) ----
        float h2;
        {
            const float* accL = (const float*)(smem + 32768);
            const int hq = hl >> 4, cidx = hl & 15;
            const int off = bl * 17 + cidx;
            const float pi = accL[(0 + hq) * 272 + off] + bias_[0];
            const float pf = accL[(2 + hq) * 272 + off] + bias_[1];
            const float pg = accL[(4 + hq) * 272 + off] + bias_[2];
            const float po = accL[(6 + hq) * 272 + off] + bias_[3];
            const float si = 1.f / (1.f + __expf(-pi));
            const float sf = 1.f / (1.f + __expf(-pf));
            const float so = 1.f / (1.f + __expf(-po));
            float e2 = __expf(-2.f * fabsf(pg));
            float tg = (1.f - e2) / (1.f + e2);
            tg = (pg < 0.f) ? -tg : tg;
            c = sf * c + si * tg;
            float e2c = __expf(-2.f * fabsf(c));
            float tc = (1.f - e2c) / (1.f + e2c);
            tc = (c < 0.f) ? -tc : tc;
            h2 = so * tc;
            // epoch-tagged h store (fire-and-forget, device-visible)
            const _Float16 hh = (_Float16)h2;
            const unsigned int hv =
                ((unsigned int)(t + 1) << 16) |
                (unsigned int)__builtin_bit_cast(unsigned short, hh);
            const void* hp = hWr + (size_t)nxt * NB * NH;
            asm volatile("global_store_dword %0, %1, off sc0 sc1"
                         :: "v"(hp), "v"(hv) : "memory");
        }
        hsOut[(size_t)t * NH] = h2;   // fire-and-forget HBM store
    }
}

extern "C" void kernel_launch(void* const* d_in, const int* in_sizes, int n_in,
                              void* d_out, int out_size, void* d_ws, size_t ws_size,
                              hipStream_t stream) {
    const float* x     = (const float*)d_in[0];
    const float* Wattn = (const float*)d_in[1];
    // d_in[2] = b_attn : provably unused (softmax shift invariance)
    const float* Wih   = (const float*)d_in[3];
    const float* Whh   = (const float*)d_in[4];
    const float* bih   = (const float*)d_in[5];
    const float* bhh   = (const float*)d_in[6];

    float* ws_out = (float*)d_out;                                 // [B][L][D]
    float* hs_out = ws_out + (size_t)NB * NL * ND;                 // [B][L][H]

    char* ws = (char*)d_ws;
    float*    attn  = (float*)(ws + 4096);                         // 256 KB
    float*    xproj = (float*)(ws + 4096 + 262144);                // 256 KB
    unsigned int* h32 = (unsigned int*)(ws + 1048576);             // 2 x 512 KB tagged
    _Float16* whhHi = (_Float16*)(ws + 2097152);                   // 2 MB
    _Float16* whhLo = (_Float16*)(ws + 2097152 + 2097152);         // 2 MB
    _Float16* wih16 = (_Float16*)(ws + 6291456);                   // 1 MB
    _Float16* w16   = (_Float16*)(ws + 8388608);                   // 33.5 MB

    // Clear epoch tags: prevents stale tag collision across timed replays.
    hipMemsetAsync(h32, 0, (size_t)2 * NB * NH * 4, stream);

    k_xproj  <<<16384, 256, 0, stream>>>(x, Wattn, xproj);
    k_softmax<<<256,   256, 0, stream>>>(xproj, attn);
    k_trans  <<<4096,  256, 0, stream>>>(x, attn, ws_out, w16);
    k_wsplit <<<4096,  256, 0, stream>>>(Whh, Wih, whhHi, whhLo, wih16);
    k_recur  <<<256,   512, 0, stream>>>(whhHi, whhLo, wih16, w16, bih, bhh,
                                         h32, hs_out);
}